// Round 9
// baseline (170.011 us; speedup 1.0000x reference)
//
#include <hip/hip_runtime.h>
#include <math.h>

// Problem constants
#define BB    16      // batch
#define CC    64      // channels
#define HW    441     // h*w
#define QP    448     // HW padded to 28 tiles of 16
#define NCLS  10
#define MM    2205
#define MP2   2304    // m padded to 144 tiles of 16
#define CH_T  8       // m-tiles per chunk = 4 pairs, one pair per wave
#define CH_B  (CH_T * 16 * CC * 2)   // 16384 bytes per chunk
#define NCH   9       // chunks per m-half (72 tiles each)
#define NQT   4       // q-tiles per block (64 queries)

typedef _Float16 half8 __attribute__((ext_vector_type(8)));
typedef float   float4_ __attribute__((ext_vector_type(4)));

// s_waitcnt with vmcnt(n), lgkmcnt/expcnt = no-wait (gfx9 encoding)
#define WAIT_VMCNT(n) __builtin_amdgcn_s_waitcnt(0x0F70 | (n))

// async global->LDS 16B per lane; lds dest = wave-uniform base + lane*16
#define GLDS16(g, l) __builtin_amdgcn_global_load_lds(                         \
    (const __attribute__((address_space(1))) unsigned int*)(const void*)(g),   \
    (__attribute__((address_space(3))) unsigned int*)(void*)(l), 16, 0, 0)

// sorted top-3 insert (a0>=a1>=a2): 3 ops via med3
__device__ __forceinline__ void ins3(float d, float& a0, float& a1, float& a2) {
    float n0 = fmaxf(d, a0);
    float n1 = __builtin_amdgcn_fmed3f(d, a0, a1);
    float n2 = __builtin_amdgcn_fmed3f(d, a1, a2);
    a0 = n0; a1 = n1; a2 = n2;
}

// ---- fused prep: normalize queries (linear fp16) + supports (fp16, XOR-swizzled
// piece order) with LDS-transposed fully-coalesced 4KB block stores ----
__global__ __launch_bounds__(256) void prep(const float* __restrict__ x1,
                                            const float* __restrict__ x2,
                                            _Float16* __restrict__ qn,
                                            _Float16* __restrict__ sn) {
    __shared__ float ssred[256];
    __shared__ half8 obuf[256];     // 32 descriptors x 8 pieces = 4KB
    int tid = threadIdx.x;
    int ml = tid & 31, cg = tid >> 5;     // 32 descriptors x 8 c-groups
    float v[8];
    half8* dstblk;
    int wz;
    if (blockIdx.x < BB * 14) {           // queries: 16 b x 14 p-tiles of 32
        int b = blockIdx.x / 14, pt = blockIdx.x % 14;
        int p = pt * 32 + ml;
        const float* src = x1 + (size_t)b * CC * HW + p;
        bool real = p < HW;
        #pragma unroll
        for (int i = 0; i < 8; ++i) v[i] = real ? src[(size_t)(cg * 8 + i) * HW] : 0.f;
        wz = cg;                                            // linear
        dstblk = (half8*)(qn + ((size_t)(b * QP + pt * 32)) * CC);
    } else {                              // supports: 10 n x 72 m-tiles of 32
        int sb = blockIdx.x - BB * 14;
        int n = sb / 72, mt = sb % 72;
        int m = mt * 32 + ml;
        const float* src = x2 + (size_t)n * CC * MM + m;
        bool real = m < MM;
        #pragma unroll
        for (int i = 0; i < 8; ++i) v[i] = real ? src[(size_t)(cg * 8 + i) * MM] : 0.f;
        wz = cg ^ (ml & 7);                                 // bank-swizzled piece
        dstblk = (half8*)(sn + ((size_t)(n * MP2 + mt * 32)) * CC);
    }
    float ss = 0.f;
    #pragma unroll
    for (int i = 0; i < 8; ++i) ss += v[i] * v[i];
    ssred[tid] = ss;
    __syncthreads();
    float tot = 0.f;
    #pragma unroll
    for (int j = 0; j < 8; ++j) tot += ssred[j * 32 + ml];
    float inv = 1.f / fmaxf(sqrtf(tot), 1e-12f);
    half8 h;
    #pragma unroll
    for (int i = 0; i < 8; ++i) h[i] = (_Float16)(v[i] * inv);
    obuf[ml * 8 + wz] = h;
    __syncthreads();
    dstblk[tid] = obuf[tid];              // 256 x 16B contiguous
}

// ---- main: per-(b,n,qgroup,mhalf) block. Swapped-operand MFMA D[m][q]:
// lanes own queries (no col-butterfly), 4 waves split m with PRIVATE
// self-staged LDS slices (zero in-loop barriers, counted-vmcnt pipeline),
// 4 register-resident Q-tiles amortize each S-fragment read over 16 MFMAs.
// Occupancy directive: waves_per_eu(2,3) gives the allocator a >=170-VGPR
// budget under either toolchain interpretation (pool/max or pool/min),
// forbidding the 64-VGPR occupancy-chasing clamp that spilled 0.5 GB on
// some containers (round 7) while leaving the proven 86-VGPR codegen of
// the good containers untouched. Body is the verified round-1 artifact. ----
__global__ __launch_bounds__(256)
__attribute__((amdgpu_waves_per_eu(2, 3)))
void img2class_mfma(const _Float16* __restrict__ qn,
                    const _Float16* __restrict__ sn,
                    float* __restrict__ partial) {
    __shared__ half8 ldsv[2 * CH_T * 16 * 8];   // 2 bufs x 16KB; wave w owns 4KB of each
    _Float16* ldsh = (_Float16*)ldsv;
    char* lbase = (char*)ldsv;

    int mh = blockIdx.x & 1;
    int t  = blockIdx.x >> 1;
    int bn = t / 7, qg = t % 7;
    int b = bn / NCLS, n = bn % NCLS;
    int mtile0 = mh ? 72 : 0;

    int tid  = threadIdx.x;
    int wave = tid >> 6, lane = tid & 63;
    int col  = lane & 15, quad = lane >> 4;
    int q0 = qg * (NQT * 16);

    const char* sbase = (const char*)(sn + (size_t)n * MP2 * CC) + (size_t)mtile0 * 16 * CC * 2;
    int so   = wave * 4096 + lane * 16;   // global src offset within chunk
    int ldst = wave * 4096;               // lds dest base (wave-private slice)

    // prologue: chunk 0 -> buf 0 (this wave's pair of m-tiles only)
    #pragma unroll
    for (int i = 0; i < 4; ++i)
        GLDS16(sbase + so + i * 1024, lbase + ldst + i * 1024);

    // Q fragments: 4 q-tiles x (k 0-31 | 32-63), register-resident whole kernel.
    // B-operand layout: col j = lane&15 (query), k = quad*8+i.
    const half8* Qp = (const half8*)(qn + ((size_t)(b * QP + q0 + col)) * CC) + quad;
    half8 Q0[NQT], Q1[NQT];
    #pragma unroll
    for (int qt = 0; qt < NQT; ++qt) {
        Q0[qt] = Qp[qt * 128];
        Q1[qt] = Qp[qt * 128 + 4];
    }

    // per-lane top-3 per q-tile (lane's q = q0 + qt*16 + col)
    float T0[NQT], T1[NQT], T2[NQT];
    #pragma unroll
    for (int qt = 0; qt < NQT; ++qt) { T0[qt] = -1.0e30f; T1[qt] = -1.0e30f; T2[qt] = -1.0e30f; }

    // S-fragment (A-operand) offsets within wave slice: row i = col (descriptor),
    // piece (quad | 4+quad) XOR-unswizzled by (row&7) == (col&7) for rows col, col+16
    int offE0 = col * CC + ((quad       ^ (col & 7)) << 3);
    int offE1 = col * CC + (((4 + quad) ^ (col & 7)) << 3);

    for (int c = 0; c < NCH; ++c) {
        if (c + 1 < NCH) {
            __builtin_amdgcn_sched_barrier(0);
            const char* g = sbase + (size_t)(c + 1) * CH_B + so;
            char* l = lbase + ((c + 1) & 1) * CH_B + ldst;
            #pragma unroll
            for (int i = 0; i < 4; ++i)
                GLDS16(g + i * 1024, l + i * 1024);
            WAIT_VMCNT(4);     // current chunk resident; prefetch stays in flight
        } else {
            WAIT_VMCNT(0);
        }
        __builtin_amdgcn_sched_barrier(0);   // keep ds_reads below the waitcnt

        const _Float16* lw = ldsh + (c & 1) * (CH_T * 16 * CC) + wave * (32 * CC);
        half8 S0e = *(const half8*)(lw + offE0);
        half8 S1e = *(const half8*)(lw + offE1);
        half8 S0o = *(const half8*)(lw + offE0 + 16 * CC);
        half8 S1o = *(const half8*)(lw + offE1 + 16 * CC);

        // pad penalty (only last chunk reaches m >= MM; wave-uniform branch)
        int tE = mtile0 + c * CH_T + wave * 2;
        bool dopen = (tE >= 136);
        float pE0 = 0.f, pE1 = 0.f, pE2 = 0.f, pE3 = 0.f;
        float pO0 = 0.f, pO1 = 0.f, pO2 = 0.f, pO3 = 0.f;
        if (dopen) {
            int mE = tE * 16 + quad * 4;
            pE0 = (mE +  0 >= MM) ? -1.0e30f : 0.f;
            pE1 = (mE +  1 >= MM) ? -1.0e30f : 0.f;
            pE2 = (mE +  2 >= MM) ? -1.0e30f : 0.f;
            pE3 = (mE +  3 >= MM) ? -1.0e30f : 0.f;
            pO0 = (mE + 16 >= MM) ? -1.0e30f : 0.f;
            pO1 = (mE + 17 >= MM) ? -1.0e30f : 0.f;
            pO2 = (mE + 18 >= MM) ? -1.0e30f : 0.f;
            pO3 = (mE + 19 >= MM) ? -1.0e30f : 0.f;
        }

        float4_ z = {0.f, 0.f, 0.f, 0.f};
        #pragma unroll
        for (int qt = 0; qt < NQT; ++qt) {
            // D[i=m][j=q]: rows quad*4+r are m within tile, col = q within tile
            float4_ ae = __builtin_amdgcn_mfma_f32_16x16x32_f16(S0e, Q0[qt], z, 0, 0, 0);
            ae = __builtin_amdgcn_mfma_f32_16x16x32_f16(S1e, Q1[qt], ae, 0, 0, 0);
            float4_ ao = __builtin_amdgcn_mfma_f32_16x16x32_f16(S0o, Q0[qt], z, 0, 0, 0);
            ao = __builtin_amdgcn_mfma_f32_16x16x32_f16(S1o, Q1[qt], ao, 0, 0, 0);
            if (dopen) {
                ae.x += pE0; ae.y += pE1; ae.z += pE2; ae.w += pE3;
                ao.x += pO0; ao.y += pO1; ao.z += pO2; ao.w += pO3;
            }
            // pair-max filter over (m, m+16), then 3-op inserts into this
            // lane's own q top-3 (identical candidate set to prior kernel)
            float d0 = fmaxf(ae.x, ao.x);
            float d1 = fmaxf(ae.y, ao.y);
            float d2 = fmaxf(ae.z, ao.z);
            float d3 = fmaxf(ae.w, ao.w);
            ins3(d0, T0[qt], T1[qt], T2[qt]);
            ins3(d1, T0[qt], T1[qt], T2[qt]);
            ins3(d2, T0[qt], T1[qt], T2[qt]);
            ins3(d3, T0[qt], T1[qt], T2[qt]);
        }
    }

    // merge across the 4 quads (disjoint m rows, same q): 2-step butterfly
    #pragma unroll
    for (int step = 16; step <= 32; step <<= 1) {
        #pragma unroll
        for (int qt = 0; qt < NQT; ++qt) {
            float o0 = __shfl_xor(T0[qt], step);
            float o1 = __shfl_xor(T1[qt], step);
            float o2 = __shfl_xor(T2[qt], step);
            ins3(o0, T0[qt], T1[qt], T2[qt]);
            ins3(o1, T0[qt], T1[qt], T2[qt]);
            ins3(o2, T0[qt], T1[qt], T2[qt]);
        }
    }

    // dump per-wave per-q top-3 into this wave's (fully consumed) buf0 slice
    float* dumpW = (float*)(lbase + wave * 4096);
    if (quad == 0) {
        #pragma unroll
        for (int qt = 0; qt < NQT; ++qt) {
            float* dp = dumpW + (qt * 16 + col) * 3;
            dp[0] = T0[qt]; dp[1] = T1[qt]; dp[2] = T2[qt];
        }
    }
    __syncthreads();

    // cross-wave merge (waves hold disjoint m); partial layout unchanged
    if (tid < 64) {
        const float* d0 = (const float*)(lbase) + tid * 3;
        float a0 = d0[0], a1 = d0[1], a2 = d0[2];
        #pragma unroll
        for (int w = 1; w < 4; ++w) {
            const float* dw = (const float*)(lbase + w * 4096) + tid * 3;
            ins3(dw[0], a0, a1, a2);
            ins3(dw[1], a0, a1, a2);
            ins3(dw[2], a0, a1, a2);
        }
        float* pp = partial + ((size_t)((bn * 7 + qg) * 2 + mh) * 64 + tid) * 3;
        pp[0] = a0; pp[1] = a1; pp[2] = a2;
    }
}

// ---- merge the two m-halves per query, sum top-3, reduce over queries ----
__global__ __launch_bounds__(512) void merge_halves(const float* __restrict__ partial,
                                                    float* __restrict__ out) {
    __shared__ float red[512];
    int bn = blockIdx.x;
    int q  = threadIdx.x;
    float s = 0.f;
    if (q < HW) {
        int qg = q >> 6, ql = q & 63;
        const float* p0 = partial + ((size_t)((bn * 7 + qg) * 2 + 0) * 64 + ql) * 3;
        const float* p1 = partial + ((size_t)((bn * 7 + qg) * 2 + 1) * 64 + ql) * 3;
        float a0 = p0[0], a1 = p0[1], a2 = p0[2];
        ins3(p1[0], a0, a1, a2);
        ins3(p1[1], a0, a1, a2);
        ins3(p1[2], a0, a1, a2);
        s = a0 + a1 + a2;
    }
    red[q] = s;
    __syncthreads();
    #pragma unroll
    for (int stride = 256; stride >= 1; stride >>= 1) {
        if (q < stride) red[q] += red[q + stride];
        __syncthreads();
    }
    if (q == 0) out[bn] = red[0];
}

extern "C" void kernel_launch(void* const* d_in, const int* in_sizes, int n_in,
                              void* d_out, int out_size, void* d_ws, size_t ws_size,
                              hipStream_t stream) {
    const float* x1 = (const float*)d_in[0];   // [16,64,21,21]
    const float* x2 = (const float*)d_in[1];   // [10,64,2205]
    float* out = (float*)d_out;                // [16,10]

    _Float16* qn   = (_Float16*)d_ws;                  // 16*448*64 halves
    _Float16* sn   = qn + (size_t)BB * QP * CC;        // 10*2304*64 halves, swizzled
    float* partial = (float*)(sn + (size_t)NCLS * MP2 * CC);  // 2240*64*3 floats

    prep<<<BB * 14 + NCLS * 72, 256, 0, stream>>>(x1, x2, qn, sn);
    img2class_mfma<<<BB * NCLS * 7 * 2, 256, 0, stream>>>(qn, sn, partial);
    merge_halves<<<BB * NCLS, 512, 0, stream>>>(partial, out);
}

// Round 10
// 135.814 us; speedup vs baseline: 1.2518x; 1.2518x over previous
//
#include <hip/hip_runtime.h>
#include <math.h>

// Problem constants
#define BB    16      // batch
#define CC    64      // channels
#define HW    441     // h*w
#define QP    448     // HW padded to 28 tiles of 16
#define NCLS  10
#define MM    2205
#define MP2   2304    // m padded to 144 tiles of 16
#define CH_T  8       // m-tiles per chunk = 4 pairs, one pair per wave
#define CH_B  (CH_T * 16 * CC * 2)   // 16384 bytes per chunk
#define NCH   9       // chunks per m-half (72 tiles each)
#define NQT   2       // q-tiles per block (32 queries) — keeps live pressure < 64 VGPR
#define NQG   14      // q-groups (14 x 32 = 448)

typedef _Float16 half8 __attribute__((ext_vector_type(8)));
typedef float   float4_ __attribute__((ext_vector_type(4)));

// s_waitcnt with vmcnt(n), lgkmcnt/expcnt = no-wait (gfx9 encoding)
#define WAIT_VMCNT(n) __builtin_amdgcn_s_waitcnt(0x0F70 | (n))

// async global->LDS 16B per lane; lds dest = wave-uniform base + lane*16
#define GLDS16(g, l) __builtin_amdgcn_global_load_lds(                         \
    (const __attribute__((address_space(1))) unsigned int*)(const void*)(g),   \
    (__attribute__((address_space(3))) unsigned int*)(void*)(l), 16, 0, 0)

// sorted top-3 insert (a0>=a1>=a2): 3 ops via med3
__device__ __forceinline__ void ins3(float d, float& a0, float& a1, float& a2) {
    float n0 = fmaxf(d, a0);
    float n1 = __builtin_amdgcn_fmed3f(d, a0, a1);
    float n2 = __builtin_amdgcn_fmed3f(d, a1, a2);
    a0 = n0; a1 = n1; a2 = n2;
}

// ---- fused prep: normalize queries (linear fp16) + supports (fp16, XOR-swizzled
// piece order) with LDS-transposed fully-coalesced 4KB block stores ----
__global__ __launch_bounds__(256) void prep(const float* __restrict__ x1,
                                            const float* __restrict__ x2,
                                            _Float16* __restrict__ qn,
                                            _Float16* __restrict__ sn) {
    __shared__ float ssred[256];
    __shared__ half8 obuf[256];     // 32 descriptors x 8 pieces = 4KB
    int tid = threadIdx.x;
    int ml = tid & 31, cg = tid >> 5;     // 32 descriptors x 8 c-groups
    float v[8];
    half8* dstblk;
    int wz;
    if (blockIdx.x < BB * 14) {           // queries: 16 b x 14 p-tiles of 32
        int b = blockIdx.x / 14, pt = blockIdx.x % 14;
        int p = pt * 32 + ml;
        const float* src = x1 + (size_t)b * CC * HW + p;
        bool real = p < HW;
        #pragma unroll
        for (int i = 0; i < 8; ++i) v[i] = real ? src[(size_t)(cg * 8 + i) * HW] : 0.f;
        wz = cg;                                            // linear
        dstblk = (half8*)(qn + ((size_t)(b * QP + pt * 32)) * CC);
    } else {                              // supports: 10 n x 72 m-tiles of 32
        int sb = blockIdx.x - BB * 14;
        int n = sb / 72, mt = sb % 72;
        int m = mt * 32 + ml;
        const float* src = x2 + (size_t)n * CC * MM + m;
        bool real = m < MM;
        #pragma unroll
        for (int i = 0; i < 8; ++i) v[i] = real ? src[(size_t)(cg * 8 + i) * MM] : 0.f;
        wz = cg ^ (ml & 7);                                 // bank-swizzled piece
        dstblk = (half8*)(sn + ((size_t)(n * MP2 + mt * 32)) * CC);
    }
    float ss = 0.f;
    #pragma unroll
    for (int i = 0; i < 8; ++i) ss += v[i] * v[i];
    ssred[tid] = ss;
    __syncthreads();
    float tot = 0.f;
    #pragma unroll
    for (int j = 0; j < 8; ++j) tot += ssred[j * 32 + ml];
    float inv = 1.f / fmaxf(sqrtf(tot), 1e-12f);
    half8 h;
    #pragma unroll
    for (int i = 0; i < 8; ++i) h[i] = (_Float16)(v[i] * inv);
    obuf[ml * 8 + wz] = h;
    __syncthreads();
    dstblk[tid] = obuf[tid];              // 256 x 16B contiguous
}

// ---- main: per-(b,n,qgroup,mhalf) block. Swapped-operand MFMA D[m][q]:
// lanes own queries, 4 waves split m with PRIVATE self-staged LDS slices
// (zero in-loop barriers, counted-vmcnt pipeline). NQT=2 keeps TRUE live
// pressure ~52 VGPR < 64 = the 8-waves/EU clamp point every allocator
// stops at -> spill-proof on every toolchain in the heterogeneous pool
// (rounds 7-9: three directive variants all spilled 200-540 MB on the
// current pool's compiler; this removes the lottery by construction). ----
__global__ __launch_bounds__(256) void img2class_mfma(const _Float16* __restrict__ qn,
                                                      const _Float16* __restrict__ sn,
                                                      float* __restrict__ partial) {
    __shared__ half8 ldsv[2 * CH_T * 16 * 8];   // 2 bufs x 16KB; wave w owns 4KB of each
    _Float16* ldsh = (_Float16*)ldsv;
    char* lbase = (char*)ldsv;

    int mh = blockIdx.x & 1;
    int t  = blockIdx.x >> 1;
    int bn = t / NQG, qg = t % NQG;
    int b = bn / NCLS, n = bn % NCLS;
    int mtile0 = mh ? 72 : 0;

    int tid  = threadIdx.x;
    int wave = tid >> 6, lane = tid & 63;
    int col  = lane & 15, quad = lane >> 4;
    int q0 = qg * (NQT * 16);

    const char* sbase = (const char*)(sn + (size_t)n * MP2 * CC) + (size_t)mtile0 * 16 * CC * 2;
    int so   = wave * 4096 + lane * 16;   // global src offset within chunk
    int ldst = wave * 4096;               // lds dest base (wave-private slice)

    // prologue: chunk 0 -> buf 0 (this wave's pair of m-tiles only)
    #pragma unroll
    for (int i = 0; i < 4; ++i)
        GLDS16(sbase + so + i * 1024, lbase + ldst + i * 1024);

    // Q fragments: 2 q-tiles x (k 0-31 | 32-63), register-resident whole kernel.
    // B-operand layout: col j = lane&15 (query), k = quad*8+i.
    const half8* Qp = (const half8*)(qn + ((size_t)(b * QP + q0 + col)) * CC) + quad;
    half8 Q0[NQT], Q1[NQT];
    #pragma unroll
    for (int qt = 0; qt < NQT; ++qt) {
        Q0[qt] = Qp[qt * 128];
        Q1[qt] = Qp[qt * 128 + 4];
    }

    // per-lane top-3 per q-tile (lane's q = q0 + qt*16 + col)
    float T0[NQT], T1[NQT], T2[NQT];
    #pragma unroll
    for (int qt = 0; qt < NQT; ++qt) { T0[qt] = -1.0e30f; T1[qt] = -1.0e30f; T2[qt] = -1.0e30f; }

    // S-fragment (A-operand) offsets within wave slice: row i = col (descriptor),
    // piece (quad | 4+quad) XOR-unswizzled by (row&7) == (col&7) for rows col, col+16
    int offE0 = col * CC + ((quad       ^ (col & 7)) << 3);
    int offE1 = col * CC + (((4 + quad) ^ (col & 7)) << 3);

    for (int c = 0; c < NCH; ++c) {
        if (c + 1 < NCH) {
            __builtin_amdgcn_sched_barrier(0);
            const char* g = sbase + (size_t)(c + 1) * CH_B + so;
            char* l = lbase + ((c + 1) & 1) * CH_B + ldst;
            #pragma unroll
            for (int i = 0; i < 4; ++i)
                GLDS16(g + i * 1024, l + i * 1024);
            WAIT_VMCNT(4);     // current chunk resident; prefetch stays in flight
        } else {
            WAIT_VMCNT(0);
        }
        __builtin_amdgcn_sched_barrier(0);   // keep ds_reads below the waitcnt

        const _Float16* lw = ldsh + (c & 1) * (CH_T * 16 * CC) + wave * (32 * CC);
        half8 S0e = *(const half8*)(lw + offE0);
        half8 S1e = *(const half8*)(lw + offE1);
        half8 S0o = *(const half8*)(lw + offE0 + 16 * CC);
        half8 S1o = *(const half8*)(lw + offE1 + 16 * CC);

        // pad penalty (only last chunk reaches m >= MM; wave-uniform branch)
        int tE = mtile0 + c * CH_T + wave * 2;
        bool dopen = (tE >= 136);
        float pE0 = 0.f, pE1 = 0.f, pE2 = 0.f, pE3 = 0.f;
        float pO0 = 0.f, pO1 = 0.f, pO2 = 0.f, pO3 = 0.f;
        if (dopen) {
            int mE = tE * 16 + quad * 4;
            pE0 = (mE +  0 >= MM) ? -1.0e30f : 0.f;
            pE1 = (mE +  1 >= MM) ? -1.0e30f : 0.f;
            pE2 = (mE +  2 >= MM) ? -1.0e30f : 0.f;
            pE3 = (mE +  3 >= MM) ? -1.0e30f : 0.f;
            pO0 = (mE + 16 >= MM) ? -1.0e30f : 0.f;
            pO1 = (mE + 17 >= MM) ? -1.0e30f : 0.f;
            pO2 = (mE + 18 >= MM) ? -1.0e30f : 0.f;
            pO3 = (mE + 19 >= MM) ? -1.0e30f : 0.f;
        }

        float4_ z = {0.f, 0.f, 0.f, 0.f};
        #pragma unroll
        for (int qt = 0; qt < NQT; ++qt) {
            // D[i=m][j=q]: rows quad*4+r are m within tile, col = q within tile
            float4_ ae = __builtin_amdgcn_mfma_f32_16x16x32_f16(S0e, Q0[qt], z, 0, 0, 0);
            ae = __builtin_amdgcn_mfma_f32_16x16x32_f16(S1e, Q1[qt], ae, 0, 0, 0);
            float4_ ao = __builtin_amdgcn_mfma_f32_16x16x32_f16(S0o, Q0[qt], z, 0, 0, 0);
            ao = __builtin_amdgcn_mfma_f32_16x16x32_f16(S1o, Q1[qt], ao, 0, 0, 0);
            if (dopen) {
                ae.x += pE0; ae.y += pE1; ae.z += pE2; ae.w += pE3;
                ao.x += pO0; ao.y += pO1; ao.z += pO2; ao.w += pO3;
            }
            // pair-max filter over (m, m+16), then 3-op inserts into this
            // lane's own q top-3 (identical candidate set to prior kernel)
            float d0 = fmaxf(ae.x, ao.x);
            float d1 = fmaxf(ae.y, ao.y);
            float d2 = fmaxf(ae.z, ao.z);
            float d3 = fmaxf(ae.w, ao.w);
            ins3(d0, T0[qt], T1[qt], T2[qt]);
            ins3(d1, T0[qt], T1[qt], T2[qt]);
            ins3(d2, T0[qt], T1[qt], T2[qt]);
            ins3(d3, T0[qt], T1[qt], T2[qt]);
        }
    }

    // merge across the 4 quads (disjoint m rows, same q): 2-step butterfly
    #pragma unroll
    for (int step = 16; step <= 32; step <<= 1) {
        #pragma unroll
        for (int qt = 0; qt < NQT; ++qt) {
            float o0 = __shfl_xor(T0[qt], step);
            float o1 = __shfl_xor(T1[qt], step);
            float o2 = __shfl_xor(T2[qt], step);
            ins3(o0, T0[qt], T1[qt], T2[qt]);
            ins3(o1, T0[qt], T1[qt], T2[qt]);
            ins3(o2, T0[qt], T1[qt], T2[qt]);
        }
    }

    // dump per-wave per-q top-3 into this wave's (fully consumed) buf0 slice
    float* dumpW = (float*)(lbase + wave * 4096);
    if (quad == 0) {
        #pragma unroll
        for (int qt = 0; qt < NQT; ++qt) {
            float* dp = dumpW + (qt * 16 + col) * 3;
            dp[0] = T0[qt]; dp[1] = T1[qt]; dp[2] = T2[qt];
        }
    }
    __syncthreads();

    // cross-wave merge (waves hold disjoint m); 32 queries per block
    if (tid < NQT * 16) {
        const float* d0 = (const float*)(lbase) + tid * 3;
        float a0 = d0[0], a1 = d0[1], a2 = d0[2];
        #pragma unroll
        for (int w = 1; w < 4; ++w) {
            const float* dw = (const float*)(lbase + w * 4096) + tid * 3;
            ins3(dw[0], a0, a1, a2);
            ins3(dw[1], a0, a1, a2);
            ins3(dw[2], a0, a1, a2);
        }
        float* pp = partial + ((size_t)((bn * NQG + qg) * 2 + mh) * (NQT * 16) + tid) * 3;
        pp[0] = a0; pp[1] = a1; pp[2] = a2;
    }
}

// ---- merge the two m-halves per query, sum top-3, reduce over queries ----
__global__ __launch_bounds__(512) void merge_halves(const float* __restrict__ partial,
                                                    float* __restrict__ out) {
    __shared__ float red[512];
    int bn = blockIdx.x;
    int q  = threadIdx.x;
    float s = 0.f;
    if (q < HW) {
        int qg = q >> 5, ql = q & 31;
        const float* p0 = partial + ((size_t)((bn * NQG + qg) * 2 + 0) * 32 + ql) * 3;
        const float* p1 = partial + ((size_t)((bn * NQG + qg) * 2 + 1) * 32 + ql) * 3;
        float a0 = p0[0], a1 = p0[1], a2 = p0[2];
        ins3(p1[0], a0, a1, a2);
        ins3(p1[1], a0, a1, a2);
        ins3(p1[2], a0, a1, a2);
        s = a0 + a1 + a2;
    }
    red[q] = s;
    __syncthreads();
    #pragma unroll
    for (int stride = 256; stride >= 1; stride >>= 1) {
        if (q < stride) red[q] += red[q + stride];
        __syncthreads();
    }
    if (q == 0) out[bn] = red[0];
}

extern "C" void kernel_launch(void* const* d_in, const int* in_sizes, int n_in,
                              void* d_out, int out_size, void* d_ws, size_t ws_size,
                              hipStream_t stream) {
    const float* x1 = (const float*)d_in[0];   // [16,64,21,21]
    const float* x2 = (const float*)d_in[1];   // [10,64,2205]
    float* out = (float*)d_out;                // [16,10]

    _Float16* qn   = (_Float16*)d_ws;                  // 16*448*64 halves
    _Float16* sn   = qn + (size_t)BB * QP * CC;        // 10*2304*64 halves, swizzled
    float* partial = (float*)(sn + (size_t)NCLS * MP2 * CC);  // 4480*32*3 floats

    prep<<<BB * 14 + NCLS * 72, 256, 0, stream>>>(x1, x2, qn, sn);
    img2class_mfma<<<BB * NCLS * NQG * 2, 256, 0, stream>>>(qn, sn, partial);
    merge_halves<<<BB * NCLS, 512, 0, stream>>>(partial, out);
}

// Round 11
// 111.967 us; speedup vs baseline: 1.5184x; 1.2130x over previous
//
#include <hip/hip_runtime.h>
#include <math.h>

// Problem constants
#define BB    16      // batch
#define CC    64      // channels
#define HW    441     // h*w
#define QP    448     // HW padded to 28 tiles of 16
#define NCLS  10
#define MM    2205
#define MP2   2304    // m padded to 144 tiles of 16
#define CH_T  8       // m-tiles per chunk = 4 pairs, one pair per wave
#define CH_B  (CH_T * 16 * CC * 2)   // 16384 bytes per chunk
#define NCH   9       // chunks per m-half (72 tiles each)
#define NQT   4       // q-tiles per block (64 queries)

typedef _Float16 half8 __attribute__((ext_vector_type(8)));
typedef float   float4_ __attribute__((ext_vector_type(4)));

// s_waitcnt with vmcnt(n), lgkmcnt/expcnt = no-wait (gfx9 encoding)
#define WAIT_VMCNT(n) __builtin_amdgcn_s_waitcnt(0x0F70 | (n))

// async global->LDS 16B per lane; lds dest = wave-uniform base + lane*16
#define GLDS16(g, l) __builtin_amdgcn_global_load_lds(                         \
    (const __attribute__((address_space(1))) unsigned int*)(const void*)(g),   \
    (__attribute__((address_space(3))) unsigned int*)(void*)(l), 16, 0, 0)

// sorted top-3 insert (a0>=a1>=a2): 3 ops via med3
__device__ __forceinline__ void ins3(float d, float& a0, float& a1, float& a2) {
    float n0 = fmaxf(d, a0);
    float n1 = __builtin_amdgcn_fmed3f(d, a0, a1);
    float n2 = __builtin_amdgcn_fmed3f(d, a1, a2);
    a0 = n0; a1 = n1; a2 = n2;
}

// ---- fused prep: normalize queries (linear fp16) + supports (fp16, XOR-swizzled
// piece order) with LDS-transposed fully-coalesced 4KB block stores ----
__global__ __launch_bounds__(256) void prep(const float* __restrict__ x1,
                                            const float* __restrict__ x2,
                                            _Float16* __restrict__ qn,
                                            _Float16* __restrict__ sn) {
    __shared__ float ssred[256];
    __shared__ half8 obuf[256];     // 32 descriptors x 8 pieces = 4KB
    int tid = threadIdx.x;
    int ml = tid & 31, cg = tid >> 5;     // 32 descriptors x 8 c-groups
    float v[8];
    half8* dstblk;
    int wz;
    if (blockIdx.x < BB * 14) {           // queries: 16 b x 14 p-tiles of 32
        int b = blockIdx.x / 14, pt = blockIdx.x % 14;
        int p = pt * 32 + ml;
        const float* src = x1 + (size_t)b * CC * HW + p;
        bool real = p < HW;
        #pragma unroll
        for (int i = 0; i < 8; ++i) v[i] = real ? src[(size_t)(cg * 8 + i) * HW] : 0.f;
        wz = cg;                                            // linear
        dstblk = (half8*)(qn + ((size_t)(b * QP + pt * 32)) * CC);
    } else {                              // supports: 10 n x 72 m-tiles of 32
        int sb = blockIdx.x - BB * 14;
        int n = sb / 72, mt = sb % 72;
        int m = mt * 32 + ml;
        const float* src = x2 + (size_t)n * CC * MM + m;
        bool real = m < MM;
        #pragma unroll
        for (int i = 0; i < 8; ++i) v[i] = real ? src[(size_t)(cg * 8 + i) * MM] : 0.f;
        wz = cg ^ (ml & 7);                                 // bank-swizzled piece
        dstblk = (half8*)(sn + ((size_t)(n * MP2 + mt * 32)) * CC);
    }
    float ss = 0.f;
    #pragma unroll
    for (int i = 0; i < 8; ++i) ss += v[i] * v[i];
    ssred[tid] = ss;
    __syncthreads();
    float tot = 0.f;
    #pragma unroll
    for (int j = 0; j < 8; ++j) tot += ssred[j * 32 + ml];
    float inv = 1.f / fmaxf(sqrtf(tot), 1e-12f);
    half8 h;
    #pragma unroll
    for (int i = 0; i < 8; ++i) h[i] = (_Float16)(v[i] * inv);
    obuf[ml * 8 + wz] = h;
    __syncthreads();
    dstblk[tid] = obuf[tid];              // 256 x 16B contiguous
}

// ---- main: per-(b,n,qgroup,mhalf) block. Swapped-operand MFMA D[m][q]:
// lanes own queries (no col-butterfly), 4 waves split m with PRIVATE
// self-staged LDS slices (zero in-loop barriers, counted-vmcnt pipeline),
// 4 register-resident Q-tiles amortize each S-fragment read over 16 MFMAs.
// ANTI-UNROLL HARDENING: the chunk loop is pinned rolled (unroll(disable))
// with loop-carried incremental pointers. The current pool's compiler was
// fully unrolling the NCH=9 loop and hoisting 8 chunks' worth of prefetch
// addresses (VGPR 156 at NQT=2, round 10; spills at any budget, rounds
// 7-9). Rolled, the live set is one base + one buffer toggle ≈ the 86-VGPR
// codegen of the verified 21.4 µs artifact. No waves_per_eu / min-warps
// directive: an unconstrained allocator never spills (round-10 evidence). ----
__global__ __launch_bounds__(256) void img2class_mfma(const _Float16* __restrict__ qn,
                                                      const _Float16* __restrict__ sn,
                                                      float* __restrict__ partial) {
    __shared__ half8 ldsv[2 * CH_T * 16 * 8];   // 2 bufs x 16KB; wave w owns 4KB of each
    char* lbase = (char*)ldsv;

    int mh = blockIdx.x & 1;
    int t  = blockIdx.x >> 1;
    int bn = t / 7, qg = t % 7;
    int b = bn / NCLS, n = bn % NCLS;
    int mtile0 = mh ? 72 : 0;

    int tid  = threadIdx.x;
    int wave = tid >> 6, lane = tid & 63;
    int col  = lane & 15, quad = lane >> 4;
    int q0 = qg * (NQT * 16);

    const char* sbase = (const char*)(sn + (size_t)n * MP2 * CC) + (size_t)mtile0 * 16 * CC * 2;
    int so   = wave * 4096 + lane * 16;   // global src offset within chunk
    int ldst = wave * 4096;               // lds dest base (wave-private slice)

    // prologue: chunk 0 -> buf 0 (this wave's pair of m-tiles only)
    #pragma unroll
    for (int i = 0; i < 4; ++i)
        GLDS16(sbase + so + i * 1024, lbase + ldst + i * 1024);

    // Q fragments: 4 q-tiles x (k 0-31 | 32-63), register-resident whole kernel.
    // B-operand layout: col j = lane&15 (query), k = quad*8+i.
    const half8* Qp = (const half8*)(qn + ((size_t)(b * QP + q0 + col)) * CC) + quad;
    half8 Q0[NQT], Q1[NQT];
    #pragma unroll
    for (int qt = 0; qt < NQT; ++qt) {
        Q0[qt] = Qp[qt * 128];
        Q1[qt] = Qp[qt * 128 + 4];
    }

    // per-lane top-3 per q-tile (lane's q = q0 + qt*16 + col)
    float T0[NQT], T1[NQT], T2[NQT];
    #pragma unroll
    for (int qt = 0; qt < NQT; ++qt) { T0[qt] = -1.0e30f; T1[qt] = -1.0e30f; T2[qt] = -1.0e30f; }

    // S-fragment (A-operand) offsets within wave slice: row i = col (descriptor),
    // piece (quad | 4+quad) XOR-unswizzled by (row&7) == (col&7) for rows col, col+16
    int offE0 = col * CC + ((quad       ^ (col & 7)) << 3);
    int offE1 = col * CC + (((4 + quad) ^ (col & 7)) << 3);

    // loop-carried pointers: one live global base, two toggling LDS slices
    const char* gsrc  = sbase + so + CH_B;   // next chunk to stage
    char*       lds_a = lbase + ldst;        // buffer holding chunk c
    char*       lds_b = lbase + CH_B + ldst; // buffer receiving chunk c+1

    #pragma clang loop unroll(disable)
    for (int c = 0; c < NCH; ++c) {
        if (c + 1 < NCH) {
            __builtin_amdgcn_sched_barrier(0);
            #pragma unroll
            for (int i = 0; i < 4; ++i)
                GLDS16(gsrc + i * 1024, lds_b + i * 1024);
            gsrc += CH_B;
            WAIT_VMCNT(4);     // current chunk resident; prefetch stays in flight
        } else {
            WAIT_VMCNT(0);
        }
        __builtin_amdgcn_sched_barrier(0);   // keep ds_reads below the waitcnt

        const _Float16* lw = (const _Float16*)lds_a;
        half8 S0e = *(const half8*)(lw + offE0);
        half8 S1e = *(const half8*)(lw + offE1);
        half8 S0o = *(const half8*)(lw + offE0 + 16 * CC);
        half8 S1o = *(const half8*)(lw + offE1 + 16 * CC);

        // pad penalty (only last chunk reaches m >= MM; wave-uniform branch)
        int tE = mtile0 + c * CH_T + wave * 2;
        bool dopen = (tE >= 136);
        float pE0 = 0.f, pE1 = 0.f, pE2 = 0.f, pE3 = 0.f;
        float pO0 = 0.f, pO1 = 0.f, pO2 = 0.f, pO3 = 0.f;
        if (dopen) {
            int mE = tE * 16 + quad * 4;
            pE0 = (mE +  0 >= MM) ? -1.0e30f : 0.f;
            pE1 = (mE +  1 >= MM) ? -1.0e30f : 0.f;
            pE2 = (mE +  2 >= MM) ? -1.0e30f : 0.f;
            pE3 = (mE +  3 >= MM) ? -1.0e30f : 0.f;
            pO0 = (mE + 16 >= MM) ? -1.0e30f : 0.f;
            pO1 = (mE + 17 >= MM) ? -1.0e30f : 0.f;
            pO2 = (mE + 18 >= MM) ? -1.0e30f : 0.f;
            pO3 = (mE + 19 >= MM) ? -1.0e30f : 0.f;
        }

        float4_ z = {0.f, 0.f, 0.f, 0.f};
        #pragma unroll
        for (int qt = 0; qt < NQT; ++qt) {
            // D[i=m][j=q]: rows quad*4+r are m within tile, col = q within tile
            float4_ ae = __builtin_amdgcn_mfma_f32_16x16x32_f16(S0e, Q0[qt], z, 0, 0, 0);
            ae = __builtin_amdgcn_mfma_f32_16x16x32_f16(S1e, Q1[qt], ae, 0, 0, 0);
            float4_ ao = __builtin_amdgcn_mfma_f32_16x16x32_f16(S0o, Q0[qt], z, 0, 0, 0);
            ao = __builtin_amdgcn_mfma_f32_16x16x32_f16(S1o, Q1[qt], ao, 0, 0, 0);
            if (dopen) {
                ae.x += pE0; ae.y += pE1; ae.z += pE2; ae.w += pE3;
                ao.x += pO0; ao.y += pO1; ao.z += pO2; ao.w += pO3;
            }
            // pair-max filter over (m, m+16), then 3-op inserts into this
            // lane's own q top-3 (identical candidate set to prior kernel)
            float d0 = fmaxf(ae.x, ao.x);
            float d1 = fmaxf(ae.y, ao.y);
            float d2 = fmaxf(ae.z, ao.z);
            float d3 = fmaxf(ae.w, ao.w);
            ins3(d0, T0[qt], T1[qt], T2[qt]);
            ins3(d1, T0[qt], T1[qt], T2[qt]);
            ins3(d2, T0[qt], T1[qt], T2[qt]);
            ins3(d3, T0[qt], T1[qt], T2[qt]);
        }

        // swap LDS buffers (loop-carried, no per-iteration recompute)
        char* tmp = lds_a; lds_a = lds_b; lds_b = tmp;
    }

    // merge across the 4 quads (disjoint m rows, same q): 2-step butterfly
    #pragma unroll
    for (int step = 16; step <= 32; step <<= 1) {
        #pragma unroll
        for (int qt = 0; qt < NQT; ++qt) {
            float o0 = __shfl_xor(T0[qt], step);
            float o1 = __shfl_xor(T1[qt], step);
            float o2 = __shfl_xor(T2[qt], step);
            ins3(o0, T0[qt], T1[qt], T2[qt]);
            ins3(o1, T0[qt], T1[qt], T2[qt]);
            ins3(o2, T0[qt], T1[qt], T2[qt]);
        }
    }

    // dump per-wave per-q top-3 into this wave's (fully consumed) buf0 slice
    float* dumpW = (float*)(lbase + wave * 4096);
    if (quad == 0) {
        #pragma unroll
        for (int qt = 0; qt < NQT; ++qt) {
            float* dp = dumpW + (qt * 16 + col) * 3;
            dp[0] = T0[qt]; dp[1] = T1[qt]; dp[2] = T2[qt];
        }
    }
    __syncthreads();

    // cross-wave merge (waves hold disjoint m); partial layout unchanged
    if (tid < 64) {
        const float* d0 = (const float*)(lbase) + tid * 3;
        float a0 = d0[0], a1 = d0[1], a2 = d0[2];
        #pragma unroll
        for (int w = 1; w < 4; ++w) {
            const float* dw = (const float*)(lbase + w * 4096) + tid * 3;
            ins3(dw[0], a0, a1, a2);
            ins3(dw[1], a0, a1, a2);
            ins3(dw[2], a0, a1, a2);
        }
        float* pp = partial + ((size_t)((bn * 7 + qg) * 2 + mh) * 64 + tid) * 3;
        pp[0] = a0; pp[1] = a1; pp[2] = a2;
    }
}

// ---- merge the two m-halves per query, sum top-3, reduce over queries ----
__global__ __launch_bounds__(512) void merge_halves(const float* __restrict__ partial,
                                                    float* __restrict__ out) {
    __shared__ float red[512];
    int bn = blockIdx.x;
    int q  = threadIdx.x;
    float s = 0.f;
    if (q < HW) {
        int qg = q >> 6, ql = q & 63;
        const float* p0 = partial + ((size_t)((bn * 7 + qg) * 2 + 0) * 64 + ql) * 3;
        const float* p1 = partial + ((size_t)((bn * 7 + qg) * 2 + 1) * 64 + ql) * 3;
        float a0 = p0[0], a1 = p0[1], a2 = p0[2];
        ins3(p1[0], a0, a1, a2);
        ins3(p1[1], a0, a1, a2);
        ins3(p1[2], a0, a1, a2);
        s = a0 + a1 + a2;
    }
    red[q] = s;
    __syncthreads();
    #pragma unroll
    for (int stride = 256; stride >= 1; stride >>= 1) {
        if (q < stride) red[q] += red[q + stride];
        __syncthreads();
    }
    if (q == 0) out[bn] = red[0];
}

extern "C" void kernel_launch(void* const* d_in, const int* in_sizes, int n_in,
                              void* d_out, int out_size, void* d_ws, size_t ws_size,
                              hipStream_t stream) {
    const float* x1 = (const float*)d_in[0];   // [16,64,21,21]
    const float* x2 = (const float*)d_in[1];   // [10,64,2205]
    float* out = (float*)d_out;                // [16,10]

    _Float16* qn   = (_Float16*)d_ws;                  // 16*448*64 halves
    _Float16* sn   = qn + (size_t)BB * QP * CC;        // 10*2304*64 halves, swizzled
    float* partial = (float*)(sn + (size_t)NCLS * MP2 * CC);  // 2240*64*3 floats

    prep<<<BB * 14 + NCLS * 72, 256, 0, stream>>>(x1, x2, qn, sn);
    img2class_mfma<<<BB * NCLS * 7 * 2, 256, 0, stream>>>(qn, sn, partial);
    merge_halves<<<BB * NCLS, 512, 0, stream>>>(partial, out);
}